// Round 1
// baseline (4907.826 us; speedup 1.0000x reference)
//
#include <hip/hip_runtime.h>
#include <hip/hip_bf16.h>
#include <cstdint>
#include <cstddef>

typedef __hip_bfloat16 bf16;
typedef __attribute__((ext_vector_type(8))) short short8;
typedef __attribute__((ext_vector_type(4))) float f32x4;

struct __align__(8) bf16x4_s { bf16 x, y, z, w; };

#define N_OBS 72000
#define NB 9000
#define MPAD 72064   /* 563*128 */
#define MT 563

__device__ __forceinline__ float gelu_tanh(float x) {
    const float c = 0.7978845608028654f; // sqrt(2/pi)
    float x3 = x * x * x;
    return 0.5f * x * (1.0f + tanhf(c * (x + 0.044715f * x3)));
}

// ---------------- slot assignment (permutation-invariant scatter) ----------------
__global__ void slot_kernel(const int* __restrict__ li, int* __restrict__ cnt,
                            int* __restrict__ dst) {
    int i = blockIdx.x * 256 + threadIdx.x;
    if (i >= N_OBS) return;
    int d = li[i * 3], h = li[i * 3 + 1], w = li[i * 3 + 2];
    int flat = d * 1800 + h * 60 + w;
    int slot = atomicAdd(&cnt[flat], 1);
    dst[i] = flat * 8 + slot;
}

// ---------------- weight fp32 [B,K,N] -> bf16 [B,N,K] ----------------
__global__ void wtrans(const float* __restrict__ W, bf16* __restrict__ Wt,
                       int K, int N) {
    size_t off = (size_t)blockIdx.y * K * N;
    int idx = blockIdx.x * 256 + threadIdx.x;
    if (idx >= K * N) return;
    int k = idx / N, n = idx % N;
    Wt[off + (size_t)n * K + k] = __float2bfloat16(W[off + idx]);
}

// ---------------- x fp32 -> bf16 padded ----------------
__global__ void convx(const float* __restrict__ X, bf16* __restrict__ Y) {
    size_t base = ((size_t)blockIdx.x * 256 + threadIdx.x) * 4;
    size_t row = base >> 8;
    bf16 z = __float2bfloat16(0.0f);
    bf16x4_s o = {z, z, z, z};
    if (row < N_OBS) {
        float4 v = *(const float4*)(X + base);
        o.x = __float2bfloat16(v.x); o.y = __float2bfloat16(v.y);
        o.z = __float2bfloat16(v.z); o.w = __float2bfloat16(v.w);
    }
    *(bf16x4_s*)(Y + base) = o;
}

// ---------------- tr_x init: broadcast bg_tok ----------------
__global__ void bginit(const float* __restrict__ BG, float* __restrict__ T) {
    size_t base = ((size_t)blockIdx.x * 256 + threadIdx.x) * 4;
    size_t row = base >> 8;
    int tok = (int)(row & 7);
    int col = (int)(base & 255);
    float4 v = *(const float4*)(BG + (size_t)tok * 256 + col);
    *(float4*)(T + base) = v;
}

// ---------------- fp32 -> bf16 bulk ----------------
__global__ void conv32(const float* __restrict__ X, bf16* __restrict__ Y) {
    size_t base = ((size_t)blockIdx.x * 256 + threadIdx.x) * 4;
    float4 v = *(const float4*)(X + base);
    bf16x4_s o;
    o.x = __float2bfloat16(v.x); o.y = __float2bfloat16(v.y);
    o.z = __float2bfloat16(v.z); o.w = __float2bfloat16(v.w);
    *(bf16x4_s*)(Y + base) = o;
}

// ---------------- LayerNorm: fp32 in -> bf16 out, one wave per row ----------------
__global__ __launch_bounds__(256) void ln_kernel(const float* __restrict__ X,
                                                 bf16* __restrict__ Y,
                                                 const float* __restrict__ g,
                                                 const float* __restrict__ b) {
    int row = blockIdx.x * 4 + (threadIdx.x >> 6);
    int lane = threadIdx.x & 63;
    const float4 xv = *(const float4*)(X + (size_t)row * 256 + lane * 4);
    float s = xv.x + xv.y + xv.z + xv.w;
    float s2 = xv.x * xv.x + xv.y * xv.y + xv.z * xv.z + xv.w * xv.w;
    #pragma unroll
    for (int m = 1; m < 64; m <<= 1) {
        s += __shfl_xor(s, m, 64);
        s2 += __shfl_xor(s2, m, 64);
    }
    float mean = s * (1.0f / 256.0f);
    float var = s2 * (1.0f / 256.0f) - mean * mean;
    float rstd = rsqrtf(var + 1e-5f);
    const float4 gv = *(const float4*)(g + lane * 4);
    const float4 bv = *(const float4*)(b + lane * 4);
    bf16x4_s o;
    o.x = __float2bfloat16((xv.x - mean) * rstd * gv.x + bv.x);
    o.y = __float2bfloat16((xv.y - mean) * rstd * gv.y + bv.y);
    o.z = __float2bfloat16((xv.z - mean) * rstd * gv.z + bv.z);
    o.w = __float2bfloat16((xv.w - mean) * rstd * gv.w + bv.w);
    *(bf16x4_s*)(Y + (size_t)row * 256 + lane * 4) = o;
}

// ---------------- per-bucket attention (8 tokens x 8 kv x 8 heads x 32) ----------------
__global__ __launch_bounds__(128) void attn_kernel(const bf16* __restrict__ Q,
                                                   const bf16* __restrict__ K,
                                                   const bf16* __restrict__ V,
                                                   bf16* __restrict__ O) {
    __shared__ __align__(16) bf16 qs[2][8][256];
    __shared__ __align__(16) bf16 ks[2][8][256];
    __shared__ __align__(16) bf16 vs[2][8][256];
    int b0 = blockIdx.x * 2;
    int tid = threadIdx.x;
    for (int c = tid; c < 512; c += 128) {
        int e = c * 8;
        size_t g = (size_t)b0 * 2048 + e;
        *(uint4*)(&qs[0][0][0] + e) = *(const uint4*)(Q + g);
        *(uint4*)(&ks[0][0][0] + e) = *(const uint4*)(K + g);
        *(uint4*)(&vs[0][0][0] + e) = *(const uint4*)(V + g);
    }
    __syncthreads();
    int bu = tid >> 6;
    int head = (tid >> 3) & 7;
    int i = tid & 7;
    const float scale = 0.17677669529663687f; // 1/sqrt(32)
    float sc[8];
    float mx = -1e30f;
    #pragma unroll
    for (int j = 0; j < 8; j++) {
        float s = 0.0f;
        #pragma unroll
        for (int d = 0; d < 32; d++)
            s += __bfloat162float(qs[bu][i][head * 32 + d]) *
                 __bfloat162float(ks[bu][j][head * 32 + d]);
        s *= scale;
        sc[j] = s;
        mx = fmaxf(mx, s);
    }
    float denom = 0.0f;
    #pragma unroll
    for (int j = 0; j < 8; j++) { sc[j] = __expf(sc[j] - mx); denom += sc[j]; }
    float inv = 1.0f / denom;
    size_t orow = (size_t)(b0 + bu) * 8 + i;
    #pragma unroll
    for (int d = 0; d < 32; d++) {
        float o = 0.0f;
        #pragma unroll
        for (int j = 0; j < 8; j++)
            o += sc[j] * __bfloat162float(vs[bu][j][head * 32 + d]);
        O[orow * 256 + head * 32 + d] = __float2bfloat16(o * inv);
    }
}

// ---------------- MFMA GEMM: C[M,N] = act(A[M,K] @ Bt[N,K]^T + bias) ----------------
// MODE: 0 = bf16 out (optional scatter rows), 1 = fp32 accumulate (C += v),
//       2 = fp32 out, rows guarded < Mstore
template <bool GELU, int MODE>
__global__ __launch_bounds__(256, 2) void gemm_bt(
    const bf16* __restrict__ A, int lda,
    const bf16* __restrict__ Bt, int ldb,
    const float* __restrict__ bias,
    bf16* __restrict__ Cb, float* __restrict__ Cf, int ldc,
    const int* __restrict__ scatter, int scatterN,
    int K, int Mstore) {
    __shared__ __align__(16) bf16 As[128 * 40];
    __shared__ __align__(16) bf16 Bs[128 * 40];
    const int tid = threadIdx.x;
    const int m0 = blockIdx.x * 128;
    const int n0 = blockIdx.y * 128;
    const int wave = tid >> 6, lane = tid & 63;
    const int wm = (wave & 1) * 64, wn = (wave >> 1) * 64;
    const int m16 = lane & 15, qq = lane >> 4;

    f32x4 acc[4][4];
    #pragma unroll
    for (int i = 0; i < 4; i++)
        #pragma unroll
        for (int j = 0; j < 4; j++)
            acc[i][j] = {0.0f, 0.0f, 0.0f, 0.0f};

    const int lrow = tid >> 2;      // 0..63
    const int lq = (tid & 3) * 8;   // 0,8,16,24

    for (int k0 = 0; k0 < K; k0 += 32) {
        const uint4 av0 = *(const uint4*)(A + (size_t)(m0 + lrow) * lda + k0 + lq);
        const uint4 av1 = *(const uint4*)(A + (size_t)(m0 + lrow + 64) * lda + k0 + lq);
        const uint4 bv0 = *(const uint4*)(Bt + (size_t)(n0 + lrow) * ldb + k0 + lq);
        const uint4 bv1 = *(const uint4*)(Bt + (size_t)(n0 + lrow + 64) * ldb + k0 + lq);
        *(uint4*)(As + lrow * 40 + lq) = av0;
        *(uint4*)(As + (lrow + 64) * 40 + lq) = av1;
        *(uint4*)(Bs + lrow * 40 + lq) = bv0;
        *(uint4*)(Bs + (lrow + 64) * 40 + lq) = bv1;
        __syncthreads();
        short8 a[4], b[4];
        #pragma unroll
        for (int i = 0; i < 4; i++)
            a[i] = *(const short8*)(As + (wm + i * 16 + m16) * 40 + qq * 8);
        #pragma unroll
        for (int j = 0; j < 4; j++)
            b[j] = *(const short8*)(Bs + (wn + j * 16 + m16) * 40 + qq * 8);
        #pragma unroll
        for (int i = 0; i < 4; i++)
            #pragma unroll
            for (int j = 0; j < 4; j++)
                acc[i][j] = __builtin_amdgcn_mfma_f32_16x16x32_bf16(a[i], b[j], acc[i][j], 0, 0, 0);
        __syncthreads();
    }

    #pragma unroll
    for (int i = 0; i < 4; i++) {
        #pragma unroll
        for (int j = 0; j < 4; j++) {
            const int col = n0 + wn + j * 16 + m16;
            const float bs = bias ? bias[col] : 0.0f;
            #pragma unroll
            for (int r = 0; r < 4; r++) {
                int row = m0 + wm + i * 16 + qq * 4 + r;
                float v = acc[i][j][r] + bs;
                if (GELU) v = gelu_tanh(v);
                if (MODE == 0) {
                    int orow = row;
                    if (scatter) {
                        if (row >= scatterN) continue;
                        orow = scatter[row];
                    }
                    Cb[(size_t)orow * ldc + col] = __float2bfloat16(v);
                } else if (MODE == 1) {
                    Cf[(size_t)row * ldc + col] += v;
                } else {
                    if (row < Mstore) Cf[(size_t)row * ldc + col] = v;
                }
            }
        }
    }
}

extern "C" void kernel_launch(void* const* d_in, const int* in_sizes, int n_in,
                              void* d_out, int out_size, void* d_ws, size_t ws_size,
                              hipStream_t stream) {
    const float* x     = (const float*)d_in[0];
    const int*   li    = (const int*)d_in[1];
    const float* mlp_w = (const float*)d_in[2];
    const float* mlp_b = (const float*)d_in[3];
    const float* bg    = (const float*)d_in[4];
    const float* ln1_g = (const float*)d_in[5];
    const float* ln1_b = (const float*)d_in[6];
    const float* wq    = (const float*)d_in[7];
    const float* bq    = (const float*)d_in[8];
    const float* wk    = (const float*)d_in[9];
    const float* bk    = (const float*)d_in[10];
    const float* wv    = (const float*)d_in[11];
    const float* bv    = (const float*)d_in[12];
    const float* wo    = (const float*)d_in[13];
    const float* bo    = (const float*)d_in[14];
    const float* ln2_g = (const float*)d_in[15];
    const float* ln2_b = (const float*)d_in[16];
    const float* w1    = (const float*)d_in[17];
    const float* b1    = (const float*)d_in[18];
    const float* w2    = (const float*)d_in[19];
    const float* b2    = (const float*)d_in[20];
    const float* pw    = (const float*)d_in[21];
    const float* pb    = (const float*)d_in[22];

    char* p = (char*)d_ws;
    auto carve = [&](size_t bytes) {
        char* r = p;
        p += (bytes + 255) & ~(size_t)255;
        return r;
    };
    int*  cnt  = (int*)carve(NB * 4);
    int*  dst  = (int*)carve(N_OBS * 4);
    bf16* mlpT = (bf16*)carve((size_t)3 * 65536 * 2);
    bf16* wqT  = (bf16*)carve((size_t)8 * 65536 * 2);
    bf16* wkT  = (bf16*)carve((size_t)8 * 65536 * 2);
    bf16* wvT  = (bf16*)carve((size_t)8 * 65536 * 2);
    bf16* woT  = (bf16*)carve((size_t)8 * 65536 * 2);
    bf16* w1T  = (bf16*)carve((size_t)8 * 262144 * 2);
    bf16* w2T  = (bf16*)carve((size_t)8 * 262144 * 2);
    bf16* pwT  = (bf16*)carve((size_t)2048 * 512 * 2);
    float* tr32 = (float*)carve((size_t)MPAD * 256 * 4);
    bf16* ctx  = (bf16*)carve((size_t)MPAD * 256 * 2);
    bf16* ybuf = (bf16*)carve((size_t)MPAD * 256 * 2);
    bf16* qbuf = (bf16*)carve((size_t)MPAD * 256 * 2);
    bf16* kbuf = (bf16*)carve((size_t)MPAD * 256 * 2 * 2); // k|v contiguous
    bf16* vbuf = kbuf + (size_t)MPAD * 256;
    bf16* hbuf = kbuf;  // [MPAD,512] FFN half, aliases k|v
    bf16* trb  = kbuf;  // [9088,2048] final bf16 tr_x, aliases k|v

    hipMemsetAsync(cnt, 0, NB * 4, stream);
    slot_kernel<<<(N_OBS + 255) / 256, 256, 0, stream>>>(li, cnt, dst);

    wtrans<<<dim3(256, 3), 256, 0, stream>>>(mlp_w, mlpT, 256, 256);
    wtrans<<<dim3(256, 8), 256, 0, stream>>>(wq, wqT, 256, 256);
    wtrans<<<dim3(256, 8), 256, 0, stream>>>(wk, wkT, 256, 256);
    wtrans<<<dim3(256, 8), 256, 0, stream>>>(wv, wvT, 256, 256);
    wtrans<<<dim3(256, 8), 256, 0, stream>>>(wo, woT, 256, 256);
    wtrans<<<dim3(1024, 8), 256, 0, stream>>>(w1, w1T, 256, 1024);
    wtrans<<<dim3(1024, 8), 256, 0, stream>>>(w2, w2T, 1024, 256);
    wtrans<<<dim3(4096, 1), 256, 0, stream>>>(pw, pwT, 2048, 512);

    convx<<<18016, 256, 0, stream>>>(x, ybuf);
    bginit<<<18016, 256, 0, stream>>>(bg, tr32);

    dim3 blk(256), g2(MT, 2), g4(MT, 4);
    // MLP: fc1+gelu, fc2+gelu, fc3 (scatter into ctx)
    gemm_bt<true, 0><<<g2, blk, 0, stream>>>(ybuf, 256, mlpT, 256, mlp_b,
        qbuf, nullptr, 256, nullptr, 0, 256, 0);
    gemm_bt<true, 0><<<g2, blk, 0, stream>>>(qbuf, 256, mlpT + 65536, 256, mlp_b + 256,
        ybuf, nullptr, 256, nullptr, 0, 256, 0);
    gemm_bt<false, 0><<<g2, blk, 0, stream>>>(ybuf, 256, mlpT + 131072, 256, mlp_b + 512,
        ctx, nullptr, 256, dst, N_OBS, 256, 0);

    for (int l = 0; l < 8; ++l) {
        ln_kernel<<<18016, 256, 0, stream>>>(tr32, ybuf, ln1_g + l * 256, ln1_b + l * 256);
        gemm_bt<false, 0><<<g2, blk, 0, stream>>>(ybuf, 256, wqT + (size_t)l * 65536, 256,
            bq + l * 256, qbuf, nullptr, 256, nullptr, 0, 256, 0);
        gemm_bt<false, 0><<<g2, blk, 0, stream>>>(ctx, 256, wkT + (size_t)l * 65536, 256,
            bk + l * 256, kbuf, nullptr, 256, nullptr, 0, 256, 0);
        gemm_bt<false, 0><<<g2, blk, 0, stream>>>(ctx, 256, wvT + (size_t)l * 65536, 256,
            bv + l * 256, vbuf, nullptr, 256, nullptr, 0, 256, 0);
        attn_kernel<<<NB / 2, 128, 0, stream>>>(qbuf, kbuf, vbuf, qbuf);
        gemm_bt<false, 1><<<g2, blk, 0, stream>>>(qbuf, 256, woT + (size_t)l * 65536, 256,
            bo + l * 256, nullptr, tr32, 256, nullptr, 0, 256, 0);
        ln_kernel<<<18016, 256, 0, stream>>>(tr32, ybuf, ln2_g + l * 256, ln2_b + l * 256);
        // FFN in two N=512 halves (hbuf aliases k|v which are dead now)
        gemm_bt<true, 0><<<g4, blk, 0, stream>>>(ybuf, 256, w1T + (size_t)l * 262144, 256,
            b1 + l * 1024, hbuf, nullptr, 512, nullptr, 0, 256, 0);
        gemm_bt<false, 1><<<g2, blk, 0, stream>>>(hbuf, 512, w2T + (size_t)l * 262144, 1024,
            b2 + l * 256, nullptr, tr32, 256, nullptr, 0, 512, 0);
        gemm_bt<true, 0><<<g4, blk, 0, stream>>>(ybuf, 256, w1T + (size_t)l * 262144 + 512 * 256, 256,
            b1 + l * 1024 + 512, hbuf, nullptr, 512, nullptr, 0, 256, 0);
        gemm_bt<false, 1><<<g2, blk, 0, stream>>>(hbuf, 512, w2T + (size_t)l * 262144 + 512, 1024,
            nullptr, nullptr, tr32, 256, nullptr, 0, 512, 0);
    }

    // final projection: tr32 -> bf16 [9008,2048]; C = trb @ projT + pb, rows < 9000
    conv32<<<18016, 256, 0, stream>>>(tr32, trb);
    gemm_bt<false, 2><<<dim3(71, 4), blk, 0, stream>>>(trb, 2048, pwT, 2048, pb,
        nullptr, (float*)d_out, 512, nullptr, 0, 2048, NB);
}